// Round 8
// baseline (218.368 us; speedup 1.0000x reference)
//
#include <hip/hip_runtime.h>
#include <hip/hip_bf16.h>
#include <cstdint>

#define DIN 16
#define HD  128
#define RNG 2048    // nodes per bin (LDS accum 4*RNG floats = 32 KB)
#define LB  11      // log2(RNG)
#define MAXB 64     // max bins (N <= 131072)
#define PB  256     // partition blocks
#define SUB 8       // sub-blocks per bin in k_aggbin

static __device__ __forceinline__ void fma4(float4& a, float s, const float4 v) {
    a.x = fmaf(s, v.x, a.x);
    a.y = fmaf(s, v.y, a.y);
    a.z = fmaf(s, v.z, a.z);
    a.w = fmaf(s, v.w, a.w);
}
static __device__ __forceinline__ void add4(float4& a, const float4 v) {
    a.x += v.x; a.y += v.y; a.z += v.z; a.w += v.w;
}

// ---------------- per-block bin histogram (bin-major layout: hist[bin*PB + blk]) ----------
__global__ __launch_bounds__(256) void k_hist(const int* __restrict__ dst,
                                              int* __restrict__ hist,
                                              int E, int R, int CHK) {
    __shared__ int h[MAXB];
    int tid = threadIdx.x;
    for (int i = tid; i < R; i += 256) h[i] = 0;
    __syncthreads();
    int e0 = blockIdx.x * CHK;
    int e1 = e0 + CHK; if (e1 > E) e1 = E;
    for (int e = e0 + tid; e < e1; e += 256) atomicAdd(&h[dst[e] >> LB], 1);
    __syncthreads();
    for (int i = tid; i < R; i += 256) hist[i * PB + blockIdx.x] = h[i];
}

// ---------------- block 0: exclusive scan of hist[nh]; block 1: weight folding ----------
__global__ __launch_bounds__(256) void k_scanfold(int* __restrict__ hist, int nh,
                                                  const float* __restrict__ W1,
                                                  const float* __restrict__ b1,
                                                  const float* __restrict__ W2,
                                                  const float* __restrict__ b2,
                                                  const float* __restrict__ Wout,
                                                  const float* __restrict__ bout,
                                                  float* __restrict__ Wcp,
                                                  float* __restrict__ cbuf) {
    int tid = threadIdx.x;
    if (blockIdx.x == 0) {
        __shared__ int sd[256];
        int CH = (nh + 255) / 256;
        int c0 = tid * CH;
        int c1 = c0 + CH; if (c1 > nh) c1 = nh;
        int sum = 0;
        for (int i = c0; i < c1; i++) sum += hist[i];
        sd[tid] = sum;
        __syncthreads();
        for (int off = 1; off < 256; off <<= 1) {
            int t = (tid >= off) ? sd[tid - off] : 0;
            __syncthreads();
            sd[tid] += t;
            __syncthreads();
        }
        int base = sd[tid] - sum;
        for (int i = c0; i < c1; i++) { int t = hist[i]; hist[i] = base; base += t; }
        return;
    }
    // weight folding: Wc = W1@W2@Wout, c1 = (W2@Wout)^T b1, b'' = Wout^T b2 + bout
    __shared__ float sT[HD * 3];
    for (int idx = tid; idx < HD * 3; idx += 256) {
        int k = idx / 3, o = idx - 3 * k;
        float s = 0.f;
        for (int j = 0; j < HD; j++) s = fmaf(W2[k * HD + j], Wout[j * 3 + o], s);
        sT[idx] = s;
    }
    if (tid < 3) {
        float s = bout[tid];
        for (int j = 0; j < HD; j++) s = fmaf(b2[j], Wout[j * 3 + tid], s);
        cbuf[3 + tid] = s;
    }
    __syncthreads();
    if (tid < 3) {
        float s = 0.f;
        for (int j = 0; j < HD; j++) s = fmaf(b1[j], sT[j * 3 + tid], s);
        cbuf[tid] = s;
    }
    for (int idx = tid; idx < HD * 3; idx += 256) {
        int k = idx / 3, o = idx - 3 * k;
        float s = 0.f;
        for (int j = 0; j < HD; j++) s = fmaf(W1[k * HD + j], sT[j * 3 + o], s);
        Wcp[k * 4 + o] = s;
    }
    for (int idx = tid; idx < HD; idx += 256) Wcp[idx * 4 + 3] = 0.f;
}

// ---------------- deterministic scatter: ebin[pos] = (src, dst & (RNG-1)) ----------------
__global__ __launch_bounds__(256) void k_part(const int* __restrict__ src,
                                              const int* __restrict__ dst,
                                              const int* __restrict__ off,
                                              int2* __restrict__ ebin,
                                              int E, int R, int CHK) {
    __shared__ int cur[MAXB];
    int tid = threadIdx.x;
    int b = blockIdx.x;
    for (int i = tid; i < R; i += 256) cur[i] = off[i * PB + b];
    __syncthreads();
    int e0 = b * CHK;
    int e1 = e0 + CHK; if (e1 > E) e1 = E;
    for (int e = e0 + tid; e < e1; e += 256) {
        int s = src[e], d = dst[e];
        int pos = atomicAdd(&cur[d >> LB], 1);     // LDS atomic
        ebin[pos] = make_int2(s, d & (RNG - 1));
    }
}

// ---------------- per-bin degree count -> dinv ----------------
__global__ __launch_bounds__(1024) void k_deg(const int2* __restrict__ ebin,
                                              const int* __restrict__ off,
                                              float* __restrict__ dinv,
                                              int N, int E, int R) {
    __shared__ int c[RNG];
    int tid = threadIdx.x;
    int b = blockIdx.x;
    for (int i = tid; i < RNG; i += 1024) c[i] = 0;
    __syncthreads();
    int e0 = off[b * PB];
    int e1 = (b + 1 < R) ? off[(b + 1) * PB] : E;
    for (int e = e0 + tid; e < e1; e += 1024) atomicAdd(&c[ebin[e].y], 1);
    __syncthreads();
    int lo = b * RNG;
    for (int i = tid; i < RNG; i += 1024)
        if (lo + i < N) dinv[lo + i] = rsqrtf((float)c[i] + 1.0f);
}

// ---------------- Ys = dinv * (leakyrelu(F@Win+bin)@Wc , 1) ----------------
__global__ __launch_bounds__(256) void k_x0y(const float* __restrict__ F,
                                             const float* __restrict__ Win,
                                             const float* __restrict__ bin,
                                             const float4* __restrict__ Wcp,
                                             const float* __restrict__ dinv,
                                             float4* __restrict__ Ys, int N) {
    __shared__ float4 sWin[DIN * HD / 4];
    __shared__ float4 sWc[HD];
    __shared__ float4 sBin[HD / 4];
    __shared__ float  sF[16 * DIN];
    int tid = threadIdx.x;
    for (int i = tid; i < DIN * HD / 4; i += 256) sWin[i] = ((const float4*)Win)[i];
    for (int i = tid; i < HD; i += 256) sWc[i] = Wcp[i];
    if (tid < HD / 4) sBin[tid] = ((const float4*)bin)[tid];
    int base = blockIdx.x * 16;
    {
        int node = base + (tid >> 4);
        sF[tid] = (node < N) ? F[(size_t)base * DIN + tid] : 0.f;
    }
    __syncthreads();
    int l = tid & 15;
    int g = tid >> 4;
    int node = base + g;
    if (node >= N) return;
    float4 h0 = sBin[l * 2 + 0];
    float4 h1 = sBin[l * 2 + 1];
    #pragma unroll
    for (int k = 0; k < DIN; k++) {
        float f = sF[g * DIN + k];
        fma4(h0, f, sWin[k * 32 + l * 2 + 0]);
        fma4(h1, f, sWin[k * 32 + l * 2 + 1]);
    }
    h0.x = h0.x > 0.f ? h0.x : 0.01f * h0.x;
    h0.y = h0.y > 0.f ? h0.y : 0.01f * h0.y;
    h0.z = h0.z > 0.f ? h0.z : 0.01f * h0.z;
    h0.w = h0.w > 0.f ? h0.w : 0.01f * h0.w;
    h1.x = h1.x > 0.f ? h1.x : 0.01f * h1.x;
    h1.y = h1.y > 0.f ? h1.y : 0.01f * h1.y;
    h1.z = h1.z > 0.f ? h1.z : 0.01f * h1.z;
    h1.w = h1.w > 0.f ? h1.w : 0.01f * h1.w;
    float hv[8] = {h0.x, h0.y, h0.z, h0.w, h1.x, h1.y, h1.z, h1.w};
    float a0 = 0.f, a1 = 0.f, a2 = 0.f;
    #pragma unroll
    for (int jj = 0; jj < 8; jj++) {
        float4 wc = sWc[l * 8 + jj];
        a0 = fmaf(hv[jj], wc.x, a0);
        a1 = fmaf(hv[jj], wc.y, a1);
        a2 = fmaf(hv[jj], wc.z, a2);
    }
    #pragma unroll
    for (int off = 8; off > 0; off >>= 1) {
        a0 += __shfl_down(a0, off, 16);
        a1 += __shfl_down(a1, off, 16);
        a2 += __shfl_down(a2, off, 16);
    }
    if (l == 0) {
        float di = dinv[node];
        Ys[node] = make_float4(di * a0, di * a1, di * a2, di);
    }
}

// ---------------- binned LDS aggregation: partial[b*SUB+s][loc] = sum V[src] ------------
// branch-free body: every edge in [lo,hi) belongs to this bin by construction
__global__ __launch_bounds__(512) void k_aggbin(const int2* __restrict__ ebin,
                                                const int* __restrict__ off,
                                                const float4* __restrict__ V,
                                                float4* __restrict__ part,
                                                int E, int R) {
    __shared__ float sa[4 * RNG];   // planar layout, 32 KB
    int tid = threadIdx.x;
    int b = blockIdx.x / SUB;
    int s = blockIdx.x % SUB;
    for (int i = tid; i < 4 * RNG; i += 512) sa[i] = 0.f;
    __syncthreads();
    int e0 = off[b * PB];
    int e1 = (b + 1 < R) ? off[(b + 1) * PB] : E;
    int len = e1 - e0;
    int lo = e0 + (int)((long long)len * s / SUB);
    int hi = e0 + (int)((long long)len * (s + 1) / SUB);
    for (int e = lo + tid; e < hi; e += 512) {
        int2 ed = ebin[e];
        float4 v = V[ed.x];
        atomicAdd(&sa[ed.y], v.x);
        atomicAdd(&sa[RNG + ed.y], v.y);
        atomicAdd(&sa[2 * RNG + ed.y], v.z);
        atomicAdd(&sa[3 * RNG + ed.y], v.w);
    }
    __syncthreads();
    float4* pb = part + (size_t)(b * SUB + s) * RNG;
    for (int i = tid; i < RNG; i += 512)
        pb[i] = make_float4(sa[i], sa[RNG + i], sa[2 * RNG + i], sa[3 * RNG + i]);
}

// ---------------- combine A: Z1s[n] = di^2 * (Ys[n] + sum_s part[s][n]) ----------------
__global__ __launch_bounds__(256) void k_combA(const float4* __restrict__ Ys,
                                               const float4* __restrict__ part,
                                               const float* __restrict__ dinv,
                                               float4* __restrict__ Z1s, int N) {
    int n = blockIdx.x * blockDim.x + threadIdx.x;
    if (n >= N) return;
    int b = n >> LB, loc = n & (RNG - 1);
    float4 acc = Ys[n];
    const float4* pb = part + (size_t)b * SUB * RNG + loc;
    #pragma unroll
    for (int s = 0; s < SUB; s++) add4(acc, pb[(size_t)s * RNG]);
    float di = dinv[n];
    float d2 = di * di;
    Z1s[n] = make_float4(d2 * acc.x, d2 * acc.y, d2 * acc.z, d2 * acc.w);
}

// ---------------- combine B + epilogue ----------------
__global__ __launch_bounds__(256) void k_combB(const float4* __restrict__ Z1s,
                                               const float4* __restrict__ part,
                                               const float* __restrict__ dinv,
                                               const float* __restrict__ cbuf,
                                               float* __restrict__ out, int N) {
    int n = blockIdx.x * blockDim.x + threadIdx.x;
    if (n >= N) return;
    int b = n >> LB, loc = n & (RNG - 1);
    float di = dinv[n];
    float4 zself = Z1s[n];
    float r = zself.w / di;                 // Z1s.w = di^2*(di + sum ds); r = (Ahat*1)[n]
    float4 acc = zself;
    const float4* pb = part + (size_t)b * SUB * RNG + loc;
    #pragma unroll
    for (int s = 0; s < SUB; s++) add4(acc, pb[(size_t)s * RNG]);
    out[(size_t)n * 3 + 0] = di * acc.x + r * cbuf[0] + cbuf[3];
    out[(size_t)n * 3 + 1] = di * acc.y + r * cbuf[1] + cbuf[4];
    out[(size_t)n * 3 + 2] = di * acc.z + r * cbuf[2] + cbuf[5];
}

extern "C" void kernel_launch(void* const* d_in, const int* in_sizes, int n_in,
                              void* d_out, int out_size, void* d_ws, size_t ws_size,
                              hipStream_t stream) {
    const float* feat = (const float*)d_in[0];
    const int*   ei   = (const int*)d_in[1];
    // d_in[2] edge_type: unused (as in reference)
    const float* Win  = (const float*)d_in[3];
    const float* bin  = (const float*)d_in[4];
    const float* W1   = (const float*)d_in[5];
    const float* b1   = (const float*)d_in[6];
    const float* W2   = (const float*)d_in[7];
    const float* b2   = (const float*)d_in[8];
    const float* Wout = (const float*)d_in[9];
    const float* bout = (const float*)d_in[10];
    float* out = (float*)d_out;

    int N = in_sizes[0] / DIN;
    int E = in_sizes[2];
    const int* src = ei;
    const int* dst = ei + E;

    int R = (N + RNG - 1) / RNG;            // 49 for N=100k
    int CHK = (E + PB - 1) / PB;            // edges per partition block
    int NH = R * PB;                        // histogram entries

    char* p = (char*)d_ws;
    auto alloc = [&](size_t bytes) -> char* {
        char* q = p;
        p += (bytes + 511) & ~(size_t)511;
        return q;
    };
    int*    hist = (int*)alloc((size_t)NH * 4);                 // ~50 KB
    int2*   ebin = (int2*)alloc((size_t)E * 8);                 // 6.4 MB
    float4* part = (float4*)alloc((size_t)R * SUB * RNG * 16);  // 12.8 MB
    float4* Ys   = (float4*)alloc((size_t)N * 16);
    float4* Z1s  = (float4*)alloc((size_t)N * 16);
    float*  dinv = (float*)alloc((size_t)N * 4);
    float*  Wcp  = (float*)alloc(HD * 4 * 4);
    float*  cbuf = (float*)alloc(8 * 4);

    k_hist<<<PB, 256, 0, stream>>>(dst, hist, E, R, CHK);
    k_scanfold<<<2, 256, 0, stream>>>(hist, NH, W1, b1, W2, b2, Wout, bout, Wcp, cbuf);
    k_part<<<PB, 256, 0, stream>>>(src, dst, hist, ebin, E, R, CHK);
    k_deg<<<R, 1024, 0, stream>>>(ebin, hist, dinv, N, E, R);
    k_x0y<<<(N + 15) / 16, 256, 0, stream>>>(feat, Win, bin, (const float4*)Wcp,
                                             dinv, Ys, N);
    k_aggbin<<<R * SUB, 512, 0, stream>>>(ebin, hist, Ys, part, E, R);
    k_combA<<<(N + 255) / 256, 256, 0, stream>>>(Ys, part, dinv, Z1s, N);
    k_aggbin<<<R * SUB, 512, 0, stream>>>(ebin, hist, Z1s, part, E, R);
    k_combB<<<(N + 255) / 256, 256, 0, stream>>>(Z1s, part, dinv, cbuf, out, N);
}